// Round 1
// baseline (184.908 us; speedup 1.0000x reference)
//
#include <hip/hip_runtime.h>

#define IH 256
#define IW 256

// ---------------- pad source (256x256x3 f32) -> float4 plane in ws ----------
__global__ __launch_bounds__(256) void pad_src_kernel(const float* __restrict__ src,
                                                      float4* __restrict__ dst) {
    int i = blockIdx.x * blockDim.x + threadIdx.x;
    if (i < IH * IW) {
        dst[i] = make_float4(src[3 * i + 0], src[3 * i + 1], src[3 * i + 2], 0.0f);
    }
}

// masked gather matching reference semantics: masked lanes gather index 0, value zeroed
__device__ __forceinline__ float4 gather4(const float4* __restrict__ src, int xi, int yi, bool inb) {
    int idx = inb ? (yi * IW + xi) : 0;
    float m = inb ? 1.0f : 0.0f;
    float4 v = src[idx];
    v.x *= m; v.y *= m; v.z *= m;
    return v;
}

__device__ __forceinline__ void sample_one(const float4* __restrict__ src,
                                           float gx, float gy, float* o) {
    float x = (gx + 1.0f) * (IW * 0.5f) - 0.5f;
    float y = (gy + 1.0f) * (IH * 0.5f) - 0.5f;
    float xwf = floorf(x), ynf = floorf(y);
    float w = x - xwf, e = 1.0f - w;   // frac east, west-weight
    float n = y - ynf, s = 1.0f - n;
    int xw = (int)xwf, yn = (int)ynf;
    int xe = xw + 1, ys = yn + 1;
    // inb(v, hi): v > -1 && v < hi  (v is an integer-valued float)
    bool mw = (xw >= 0) && (xw < IW);
    bool me = (xe >= 0) && (xe < IW);
    bool mn = (yn >= 0) && (yn < IH);
    bool ms = (ys >= 0) && (ys < IH);
    float4 vnw = gather4(src, xw, yn, mn && mw);
    float4 vne = gather4(src, xe, yn, mn && me);
    float4 vsw = gather4(src, xw, ys, ms && mw);
    float4 vse = gather4(src, xe, ys, ms && me);
    float wnw = s * e, wne = s * w, wsw = n * e, wse = n * w;
    o[0] = wnw * vnw.x + wsw * vsw.x + wne * vne.x + wse * vse.x;
    o[1] = wnw * vnw.y + wsw * vsw.y + wne * vne.y + wse * vse.y;
    o[2] = wnw * vnw.z + wsw * vsw.z + wne * vne.z + wse * vse.z;
}

// ---------------- main kernel: 4 pixels / thread, padded float4 source -------
__global__ __launch_bounds__(256) void deform_kernel(const float4* __restrict__ mot4,
                                                     const float4* __restrict__ src,
                                                     float4* __restrict__ out4,
                                                     int nquads) {
    int tid = blockIdx.x * blockDim.x + threadIdx.x;  // one thread = 4 pixels
    if (tid >= nquads) return;
    float4 m01 = mot4[(size_t)tid * 2 + 0];
    float4 m23 = mot4[(size_t)tid * 2 + 1];
    float r[12];
    sample_one(src, m01.x, m01.y, r + 0);
    sample_one(src, m01.z, m01.w, r + 3);
    sample_one(src, m23.x, m23.y, r + 6);
    sample_one(src, m23.z, m23.w, r + 9);
    float4* o = out4 + (size_t)tid * 3;
    o[0] = make_float4(r[0], r[1], r[2], r[3]);
    o[1] = make_float4(r[4], r[5], r[6], r[7]);
    o[2] = make_float4(r[8], r[9], r[10], r[11]);
}

// ---------------- fallback: gather straight from 3-channel source ------------
__device__ __forceinline__ void gather3(const float* __restrict__ src, int xi, int yi, bool inb,
                                        float* vx, float* vy, float* vz) {
    int idx = inb ? (yi * IW + xi) * 3 : 0;
    float m = inb ? 1.0f : 0.0f;
    *vx = m * src[idx + 0];
    *vy = m * src[idx + 1];
    *vz = m * src[idx + 2];
}

__device__ __forceinline__ void sample_one_direct(const float* __restrict__ src,
                                                  float gx, float gy, float* o) {
    float x = (gx + 1.0f) * (IW * 0.5f) - 0.5f;
    float y = (gy + 1.0f) * (IH * 0.5f) - 0.5f;
    float xwf = floorf(x), ynf = floorf(y);
    float w = x - xwf, e = 1.0f - w;
    float n = y - ynf, s = 1.0f - n;
    int xw = (int)xwf, yn = (int)ynf;
    int xe = xw + 1, ys = yn + 1;
    bool mw = (xw >= 0) && (xw < IW);
    bool me = (xe >= 0) && (xe < IW);
    bool mn = (yn >= 0) && (yn < IH);
    bool ms = (ys >= 0) && (ys < IH);
    float nwx, nwy, nwz, nex, ney, nez, swx, swy, swz, sex, sey, sez;
    gather3(src, xw, yn, mn && mw, &nwx, &nwy, &nwz);
    gather3(src, xe, yn, mn && me, &nex, &ney, &nez);
    gather3(src, xw, ys, ms && mw, &swx, &swy, &swz);
    gather3(src, xe, ys, ms && me, &sex, &sey, &sez);
    float wnw = s * e, wne = s * w, wsw = n * e, wse = n * w;
    o[0] = wnw * nwx + wsw * swx + wne * nex + wse * sex;
    o[1] = wnw * nwy + wsw * swy + wne * ney + wse * sey;
    o[2] = wnw * nwz + wsw * swz + wne * nez + wse * sez;
}

__global__ __launch_bounds__(256) void deform_direct_kernel(const float4* __restrict__ mot4,
                                                            const float* __restrict__ src,
                                                            float4* __restrict__ out4,
                                                            int nquads) {
    int tid = blockIdx.x * blockDim.x + threadIdx.x;
    if (tid >= nquads) return;
    float4 m01 = mot4[(size_t)tid * 2 + 0];
    float4 m23 = mot4[(size_t)tid * 2 + 1];
    float r[12];
    sample_one_direct(src, m01.x, m01.y, r + 0);
    sample_one_direct(src, m01.z, m01.w, r + 3);
    sample_one_direct(src, m23.x, m23.y, r + 6);
    sample_one_direct(src, m23.z, m23.w, r + 9);
    float4* o = out4 + (size_t)tid * 3;
    o[0] = make_float4(r[0], r[1], r[2], r[3]);
    o[1] = make_float4(r[4], r[5], r[6], r[7]);
    o[2] = make_float4(r[8], r[9], r[10], r[11]);
}

extern "C" void kernel_launch(void* const* d_in, const int* in_sizes, int n_in,
                              void* d_out, int out_size, void* d_ws, size_t ws_size,
                              hipStream_t stream) {
    const float* src = (const float*)d_in[0];      // (1, 256, 256, 3) f32
    const float* mot = (const float*)d_in[1];      // (8, 11, 256, 256, 2) f32
    float* out = (float*)d_out;                    // (88, 65536, 3) f32

    const int npix = in_sizes[1] / 2;              // 88 * 65536 pixels
    const int nquads = npix / 4;                   // 4 pixels per thread
    const int threads = 256;

    if (ws_size >= (size_t)IH * IW * sizeof(float4)) {
        float4* pad = (float4*)d_ws;
        pad_src_kernel<<<(IH * IW + threads - 1) / threads, threads, 0, stream>>>(src, pad);
        deform_kernel<<<(nquads + threads - 1) / threads, threads, 0, stream>>>(
            (const float4*)mot, (const float4*)pad, (float4*)out, nquads);
    } else {
        deform_direct_kernel<<<(nquads + threads - 1) / threads, threads, 0, stream>>>(
            (const float4*)mot, src, (float4*)out, nquads);
    }
}

// Round 2
// 154.650 us; speedup vs baseline: 1.1957x; 1.1957x over previous
//
#include <hip/hip_runtime.h>
#include <hip/hip_fp16.h>

#define IH 256
#define IW 256
#define NW 257              // node grid is 257x257 (bases -1..255)
#define NODE_BYTES 32       // 12 fp16 + 4 pad halves

// ============================================================================
// Node-table path: node (y,x) holds the 2x2 corner block for base
// (yn=y-1, xw=x-1), channels as fp16, OOB corners = 0 (== reference masking,
// since xw,yn ∈ [-1,255] and xe,ys ∈ [0,256] — OOB is only ever the ±1 border).
// Layout (halves): [0..2]=nw.xyz [3..5]=ne.xyz [6..8]=sw.xyz [9..11]=se.xyz
// ============================================================================

__global__ __launch_bounds__(256) void build_nodes_kernel(const float* __restrict__ src,
                                                          uint4* __restrict__ nodes) {
    int i = blockIdx.x * blockDim.x + threadIdx.x;
    if (i >= NW * NW) return;
    int ny = i / NW, nx = i - ny * NW;
    int yn = ny - 1, xw = nx - 1;

    union { ushort h[16]; uint4 v[2]; } nu;
    #pragma unroll
    for (int k = 0; k < 16; ++k) nu.h[k] = 0;

    #pragma unroll
    for (int c = 0; c < 4; ++c) {           // nw, ne, sw, se
        int dy = c >> 1, dx = c & 1;
        int r = yn + dy, cc = xw + dx;
        bool ok = (r >= 0) && (r < IH) && (cc >= 0) && (cc < IW);
        int base = ok ? (r * IW + cc) * 3 : 0;
        float m = ok ? 1.0f : 0.0f;
        #pragma unroll
        for (int ch = 0; ch < 3; ++ch) {
            float v = m * src[base + ch];
            nu.h[c * 3 + ch] = __half_as_ushort(__float2half(v));
        }
    }
    nodes[i * 2 + 0] = nu.v[0];
    nodes[i * 2 + 1] = nu.v[1];
}

__device__ __forceinline__ void sample_node(const uint4* __restrict__ nodes,
                                            float gx, float gy, float* o) {
    float x = fmaf(gx, (float)(IW / 2), (float)(IW / 2) - 0.5f);  // (gx+1)*128-0.5
    float y = fmaf(gy, (float)(IH / 2), (float)(IH / 2) - 0.5f);
    float xf = floorf(x), yf = floorf(y);
    float w = x - xf, n = y - yf;        // east / south fracs
    float e = 1.0f - w, s = 1.0f - n;
    int nxi = (int)xf + 1;               // node coords, in [0,256]
    int nyi = (int)yf + 1;
    int node = nyi * NW + nxi;

    union { uint4 v; ushort h[8]; } ua, ub;
    ua.v = nodes[node * 2 + 0];
    ub.v = nodes[node * 2 + 1];

    float nwx = __half2float(__ushort_as_half(ua.h[0]));
    float nwy = __half2float(__ushort_as_half(ua.h[1]));
    float nwz = __half2float(__ushort_as_half(ua.h[2]));
    float nex = __half2float(__ushort_as_half(ua.h[3]));
    float ney = __half2float(__ushort_as_half(ua.h[4]));
    float nez = __half2float(__ushort_as_half(ua.h[5]));
    float swx = __half2float(__ushort_as_half(ua.h[6]));
    float swy = __half2float(__ushort_as_half(ua.h[7]));
    float swz = __half2float(__ushort_as_half(ub.h[0]));
    float sex = __half2float(__ushort_as_half(ub.h[1]));
    float sey = __half2float(__ushort_as_half(ub.h[2]));
    float sez = __half2float(__ushort_as_half(ub.h[3]));

    float wnw = s * e, wne = s * w, wsw = n * e, wse = n * w;
    o[0] = wnw * nwx + wsw * swx + wne * nex + wse * sex;
    o[1] = wnw * nwy + wsw * swy + wne * ney + wse * sey;
    o[2] = wnw * nwz + wsw * swz + wne * nez + wse * sez;
}

__global__ __launch_bounds__(256) void deform_nodes_kernel(const float4* __restrict__ mot4,
                                                           const uint4* __restrict__ nodes,
                                                           float4* __restrict__ out4,
                                                           int nquads) {
    int tid = blockIdx.x * blockDim.x + threadIdx.x;  // one thread = 4 pixels
    if (tid >= nquads) return;
    float4 m01 = mot4[(size_t)tid * 2 + 0];
    float4 m23 = mot4[(size_t)tid * 2 + 1];
    float r[12];
    sample_node(nodes, m01.x, m01.y, r + 0);
    sample_node(nodes, m01.z, m01.w, r + 3);
    sample_node(nodes, m23.x, m23.y, r + 6);
    sample_node(nodes, m23.z, m23.w, r + 9);
    float4* o = out4 + (size_t)tid * 3;
    o[0] = make_float4(r[0], r[1], r[2], r[3]);
    o[1] = make_float4(r[4], r[5], r[6], r[7]);
    o[2] = make_float4(r[8], r[9], r[10], r[11]);
}

// ============================================================================
// Fallback 1: float4-padded source (1 MB ws) — round-1 kernel
// ============================================================================
__global__ __launch_bounds__(256) void pad_src_kernel(const float* __restrict__ src,
                                                      float4* __restrict__ dst) {
    int i = blockIdx.x * blockDim.x + threadIdx.x;
    if (i < IH * IW) {
        dst[i] = make_float4(src[3 * i + 0], src[3 * i + 1], src[3 * i + 2], 0.0f);
    }
}

__device__ __forceinline__ float4 gather4(const float4* __restrict__ src, int xi, int yi, bool inb) {
    int idx = inb ? (yi * IW + xi) : 0;
    float m = inb ? 1.0f : 0.0f;
    float4 v = src[idx];
    v.x *= m; v.y *= m; v.z *= m;
    return v;
}

__device__ __forceinline__ void sample_one(const float4* __restrict__ src,
                                           float gx, float gy, float* o) {
    float x = (gx + 1.0f) * (IW * 0.5f) - 0.5f;
    float y = (gy + 1.0f) * (IH * 0.5f) - 0.5f;
    float xwf = floorf(x), ynf = floorf(y);
    float w = x - xwf, e = 1.0f - w;
    float n = y - ynf, s = 1.0f - n;
    int xw = (int)xwf, yn = (int)ynf;
    int xe = xw + 1, ys = yn + 1;
    bool mw = (xw >= 0) && (xw < IW);
    bool me = (xe >= 0) && (xe < IW);
    bool mn = (yn >= 0) && (yn < IH);
    bool ms = (ys >= 0) && (ys < IH);
    float4 vnw = gather4(src, xw, yn, mn && mw);
    float4 vne = gather4(src, xe, yn, mn && me);
    float4 vsw = gather4(src, xw, ys, ms && mw);
    float4 vse = gather4(src, xe, ys, ms && me);
    float wnw = s * e, wne = s * w, wsw = n * e, wse = n * w;
    o[0] = wnw * vnw.x + wsw * vsw.x + wne * vne.x + wse * vse.x;
    o[1] = wnw * vnw.y + wsw * vsw.y + wne * vne.y + wse * vse.y;
    o[2] = wnw * vnw.z + wsw * vsw.z + wne * vne.z + wse * vse.z;
}

__global__ __launch_bounds__(256) void deform_kernel(const float4* __restrict__ mot4,
                                                     const float4* __restrict__ src,
                                                     float4* __restrict__ out4,
                                                     int nquads) {
    int tid = blockIdx.x * blockDim.x + threadIdx.x;
    if (tid >= nquads) return;
    float4 m01 = mot4[(size_t)tid * 2 + 0];
    float4 m23 = mot4[(size_t)tid * 2 + 1];
    float r[12];
    sample_one(src, m01.x, m01.y, r + 0);
    sample_one(src, m01.z, m01.w, r + 3);
    sample_one(src, m23.x, m23.y, r + 6);
    sample_one(src, m23.z, m23.w, r + 9);
    float4* o = out4 + (size_t)tid * 3;
    o[0] = make_float4(r[0], r[1], r[2], r[3]);
    o[1] = make_float4(r[4], r[5], r[6], r[7]);
    o[2] = make_float4(r[8], r[9], r[10], r[11]);
}

// ============================================================================
// Fallback 2: direct 3-channel gather (no ws)
// ============================================================================
__device__ __forceinline__ void gather3(const float* __restrict__ src, int xi, int yi, bool inb,
                                        float* vx, float* vy, float* vz) {
    int idx = inb ? (yi * IW + xi) * 3 : 0;
    float m = inb ? 1.0f : 0.0f;
    *vx = m * src[idx + 0];
    *vy = m * src[idx + 1];
    *vz = m * src[idx + 2];
}

__device__ __forceinline__ void sample_one_direct(const float* __restrict__ src,
                                                  float gx, float gy, float* o) {
    float x = (gx + 1.0f) * (IW * 0.5f) - 0.5f;
    float y = (gy + 1.0f) * (IH * 0.5f) - 0.5f;
    float xwf = floorf(x), ynf = floorf(y);
    float w = x - xwf, e = 1.0f - w;
    float n = y - ynf, s = 1.0f - n;
    int xw = (int)xwf, yn = (int)ynf;
    int xe = xw + 1, ys = yn + 1;
    bool mw = (xw >= 0) && (xw < IW);
    bool me = (xe >= 0) && (xe < IW);
    bool mn = (yn >= 0) && (yn < IH);
    bool ms = (ys >= 0) && (ys < IH);
    float nwx, nwy, nwz, nex, ney, nez, swx, swy, swz, sex, sey, sez;
    gather3(src, xw, yn, mn && mw, &nwx, &nwy, &nwz);
    gather3(src, xe, yn, mn && me, &nex, &ney, &nez);
    gather3(src, xw, ys, ms && mw, &swx, &swy, &swz);
    gather3(src, xe, ys, ms && me, &sex, &sey, &sez);
    float wnw = s * e, wne = s * w, wsw = n * e, wse = n * w;
    o[0] = wnw * nwx + wsw * swx + wne * nex + wse * sex;
    o[1] = wnw * nwy + wsw * swy + wne * ney + wse * sey;
    o[2] = wnw * nwz + wsw * swz + wne * nez + wse * sez;
}

__global__ __launch_bounds__(256) void deform_direct_kernel(const float4* __restrict__ mot4,
                                                            const float* __restrict__ src,
                                                            float4* __restrict__ out4,
                                                            int nquads) {
    int tid = blockIdx.x * blockDim.x + threadIdx.x;
    if (tid >= nquads) return;
    float4 m01 = mot4[(size_t)tid * 2 + 0];
    float4 m23 = mot4[(size_t)tid * 2 + 1];
    float r[12];
    sample_one_direct(src, m01.x, m01.y, r + 0);
    sample_one_direct(src, m01.z, m01.w, r + 3);
    sample_one_direct(src, m23.x, m23.y, r + 6);
    sample_one_direct(src, m23.z, m23.w, r + 9);
    float4* o = out4 + (size_t)tid * 3;
    o[0] = make_float4(r[0], r[1], r[2], r[3]);
    o[1] = make_float4(r[4], r[5], r[6], r[7]);
    o[2] = make_float4(r[8], r[9], r[10], r[11]);
}

extern "C" void kernel_launch(void* const* d_in, const int* in_sizes, int n_in,
                              void* d_out, int out_size, void* d_ws, size_t ws_size,
                              hipStream_t stream) {
    const float* src = (const float*)d_in[0];      // (1, 256, 256, 3) f32
    const float* mot = (const float*)d_in[1];      // (8, 11, 256, 256, 2) f32
    float* out = (float*)d_out;                    // (88, 65536, 3) f32

    const int npix = in_sizes[1] / 2;
    const int nquads = npix / 4;
    const int threads = 256;
    const size_t node_bytes = (size_t)NW * NW * NODE_BYTES;   // ~2.11 MB

    if (ws_size >= node_bytes) {
        uint4* nodes = (uint4*)d_ws;
        build_nodes_kernel<<<(NW * NW + threads - 1) / threads, threads, 0, stream>>>(src, nodes);
        deform_nodes_kernel<<<(nquads + threads - 1) / threads, threads, 0, stream>>>(
            (const float4*)mot, nodes, (float4*)out, nquads);
    } else if (ws_size >= (size_t)IH * IW * sizeof(float4)) {
        float4* pad = (float4*)d_ws;
        pad_src_kernel<<<(IH * IW + threads - 1) / threads, threads, 0, stream>>>(src, pad);
        deform_kernel<<<(nquads + threads - 1) / threads, threads, 0, stream>>>(
            (const float4*)mot, (const float4*)pad, (float4*)out, nquads);
    } else {
        deform_direct_kernel<<<(nquads + threads - 1) / threads, threads, 0, stream>>>(
            (const float4*)mot, src, (float4*)out, nquads);
    }
}